// Round 1
// baseline (6743.669 us; speedup 1.0000x reference)
//
#include <hip/hip_runtime.h>
#include <math.h>

// Problem constants
#define NQ     25      // number of query images (= n_support)
#define NWAY   5
#define KSHOT  5
#define CC     640     // channels
#define HW     196     // 14*14
#define NSL    980     // NWAY*HW support locations
#define GAMMA  20.0f
#define GAMMA2 10.0f
#define NITER  24

// ---------------------------------------------------------------------------
// K1: prototype mean + per-spatial-location L2 normalization.
// blocks 0..24: normalize query q (feat image 25+q) -> qn[q][c][m]  (c-major)
// blocks 25..29: class prototype s = mean of images 25+5s..25+5s+4,
//                normalized, stored as sn[c][s*196+n]  (640 x 980)
// ---------------------------------------------------------------------------
__global__ __launch_bounds__(256) void k_norm(const float* __restrict__ feat,
                                              float* __restrict__ qn,
                                              float* __restrict__ sn) {
    const int b = blockIdx.x;
    const int t = threadIdx.x;
    if (t >= HW) return;
    if (b < NQ) {
        const float* f = feat + (size_t)(NQ + b) * CC * HW;
        float ss = 0.f;
        for (int c = 0; c < CC; ++c) { float x = f[c * HW + t]; ss += x * x; }
        const float inv = 1.f / (1e-16f + sqrtf(ss));
        float* o = qn + (size_t)b * CC * HW;
        for (int c = 0; c < CC; ++c) o[c * HW + t] = f[c * HW + t] * inv;
    } else {
        const int s = b - NQ;
        const float* f = feat + (size_t)(NQ + s * KSHOT) * CC * HW;
        const size_t img = (size_t)CC * HW;
        float ss = 0.f;
        for (int c = 0; c < CC; ++c) {
            float m = 0.2f * (f[c * HW + t] + f[img + c * HW + t] + f[2 * img + c * HW + t]
                              + f[3 * img + c * HW + t] + f[4 * img + c * HW + t]);
            sn[c * NSL + s * HW + t] = m;
            ss += m * m;
        }
        const float inv = 1.f / (1e-16f + sqrtf(ss));
        for (int c = 0; c < CC; ++c) sn[c * NSL + s * HW + t] *= inv;
    }
}

// ---------------------------------------------------------------------------
// K2: S[q][m][j] = sum_c qn[q][c][m] * sn[c][j]   (per-q 196x980 = A^T B GEMM)
// 64x64 tile, BK=16, 256 threads, 4x4 per thread.
// ---------------------------------------------------------------------------
__global__ __launch_bounds__(256) void k_gemm(const float* __restrict__ qn,
                                              const float* __restrict__ sn,
                                              float* __restrict__ S) {
    const int q  = blockIdx.z;
    const int m0 = blockIdx.y * 64;
    const int n0 = blockIdx.x * 64;
    const float* A = qn + (size_t)q * CC * HW;
    __shared__ float As[16][64];
    __shared__ float Bs[16][64];
    const int t  = threadIdx.x;
    const int tx = t & 15, ty = t >> 4;
    float acc[4][4] = {{0.f}};
    for (int c0 = 0; c0 < CC; c0 += 16) {
#pragma unroll
        for (int p = 0; p < 4; ++p) {
            int idx = t + p * 256;
            int k = idx >> 6, i = idx & 63;
            int m = m0 + i;
            As[k][i] = (m < HW) ? A[(c0 + k) * HW + m] : 0.f;
            int j = n0 + i;
            Bs[k][i] = (j < NSL) ? sn[(c0 + k) * NSL + j] : 0.f;
        }
        __syncthreads();
#pragma unroll
        for (int k = 0; k < 16; ++k) {
            float a[4], bb[4];
#pragma unroll
            for (int i = 0; i < 4; ++i) a[i] = As[k][ty * 4 + i];
#pragma unroll
            for (int j = 0; j < 4; ++j) bb[j] = Bs[k][tx * 4 + j];
#pragma unroll
            for (int i = 0; i < 4; ++i)
#pragma unroll
                for (int j = 0; j < 4; ++j) acc[i][j] += a[i] * bb[j];
        }
        __syncthreads();
    }
    float* Sq = S + (size_t)q * HW * NSL;
#pragma unroll
    for (int i = 0; i < 4; ++i) {
        int m = m0 + ty * 4 + i;
        if (m >= HW) continue;
#pragma unroll
        for (int j = 0; j < 4; ++j) {
            int n = n0 + tx * 4 + j;
            if (n < NSL) Sq[m * NSL + n] = acc[i][j];
        }
    }
}

// ---------------------------------------------------------------------------
// K3a: Ts[qm][j] = softmax_j(GAMMA * S[qm][:])   one block per (q,m) row
// ---------------------------------------------------------------------------
__global__ __launch_bounds__(256) void k_ts(const float* __restrict__ S,
                                            float* __restrict__ Ts) {
    const size_t qm = blockIdx.x;
    const float* row = S + qm * NSL;
    float* orow = Ts + qm * NSL;
    const int t = threadIdx.x, lane = t & 63, wv = t >> 6;
    __shared__ float redm[4], reds[4];
    float x[4];
    float mx = -1e30f;
#pragma unroll
    for (int p = 0; p < 4; ++p) {
        int j = t + p * 256;
        x[p] = (j < NSL) ? row[j] : -1e30f;
        mx = fmaxf(mx, x[p]);
    }
    for (int d = 32; d; d >>= 1) mx = fmaxf(mx, __shfl_xor(mx, d));
    if (lane == 0) redm[wv] = mx;
    __syncthreads();
    mx = fmaxf(fmaxf(redm[0], redm[1]), fmaxf(redm[2], redm[3]));
    float e[4], sum = 0.f;
#pragma unroll
    for (int p = 0; p < 4; ++p) {
        e[p] = expf(GAMMA * (x[p] - mx));   // padded lanes -> exp(-inf)=0
        sum += e[p];
    }
    for (int d = 32; d; d >>= 1) sum += __shfl_xor(sum, d);
    if (lane == 0) reds[wv] = sum;
    __syncthreads();
    const float inv = 1.f / (reds[0] + reds[1] + reds[2] + reds[3]);
#pragma unroll
    for (int p = 0; p < 4; ++p) {
        int j = t + p * 256;
        if (j < NSL) orow[j] = e[p] * inv;
    }
}

// ---------------------------------------------------------------------------
// K3b: Tq[q][m][j] = softmax over m of (GAMMA2 * S[q][:,j]); thread per column
// ---------------------------------------------------------------------------
__global__ __launch_bounds__(1024) void k_tq(const float* __restrict__ S,
                                             float* __restrict__ Tq) {
    const int q = blockIdx.x;
    const int j = threadIdx.x;
    if (j >= NSL) return;
    const float* base = S + (size_t)q * HW * NSL;
    float mx = -1e30f;
    for (int m = 0; m < HW; ++m) mx = fmaxf(mx, base[m * NSL + j]);
    float sum = 0.f;
    for (int m = 0; m < HW; ++m) sum += expf(GAMMA2 * (base[m * NSL + j] - mx));
    const float inv = 1.f / sum;
    float* o = Tq + (size_t)q * HW * NSL;
    for (int m = 0; m < HW; ++m) o[m * NSL + j] = expf(GAMMA2 * (base[m * NSL + j] - mx)) * inv;
}

// ---------------------------------------------------------------------------
// K4: per-query Katz solve via Neumann iteration + class reduce.
//   rhs[m] = 1 + 0.5 * sum_j Tq[m][j]
//   v <- rhs + 0.25 * Tq * (Ts^T v)      (x NITER, contraction 0.25/iter)
//   partial[j] = (Ts^T v)[j];  out[q][s] = sum_{j in class s} partial / total
// ---------------------------------------------------------------------------
__global__ __launch_bounds__(256) void k_solve(const float* __restrict__ Ts,
                                               const float* __restrict__ Tq,
                                               float* __restrict__ out) {
    const int q = blockIdx.x;
    const float* ts = Ts + (size_t)q * HW * NSL;
    const float* tq = Tq + (size_t)q * HW * NSL;
    __shared__ float v[HW], rhs[HW], w[NSL], cls[8];
    const int t = threadIdx.x, lane = t & 63, wv = t >> 6;

    for (int m = wv; m < HW; m += 4) {
        float s = 0.f;
        for (int j = lane; j < NSL; j += 64) s += tq[m * NSL + j];
        for (int d = 32; d; d >>= 1) s += __shfl_xor(s, d);
        if (lane == 0) { float r = 1.f + 0.5f * s; rhs[m] = r; v[m] = r; }
    }
    __syncthreads();

    for (int it = 0; it < NITER; ++it) {
        for (int j = t; j < NSL; j += 256) {
            float a = 0.f;
            for (int m = 0; m < HW; ++m) a += ts[m * NSL + j] * v[m];
            w[j] = a;
        }
        __syncthreads();
        for (int m = wv; m < HW; m += 4) {
            float s = 0.f;
            for (int j = lane; j < NSL; j += 64) s += tq[m * NSL + j] * w[j];
            for (int d = 32; d; d >>= 1) s += __shfl_xor(s, d);
            if (lane == 0) v[m] = rhs[m] + 0.25f * s;
        }
        __syncthreads();
    }

    for (int j = t; j < NSL; j += 256) {
        float a = 0.f;
        for (int m = 0; m < HW; ++m) a += ts[m * NSL + j] * v[m];
        w[j] = a;
    }
    __syncthreads();

    for (int s = wv; s < NWAY; s += 4) {
        float a = 0.f;
        for (int n = lane; n < HW; n += 64) a += w[s * HW + n];
        for (int d = 32; d; d >>= 1) a += __shfl_xor(a, d);
        if (lane == 0) cls[s] = a;
    }
    __syncthreads();
    if (t == 0) {
        float tot = cls[0] + cls[1] + cls[2] + cls[3] + cls[4];
        float invt = 1.f / tot;
        for (int s = 0; s < NWAY; ++s) out[q * NWAY + s] = cls[s] * invt;
    }
}

// ---------------------------------------------------------------------------
extern "C" void kernel_launch(void* const* d_in, const int* in_sizes, int n_in,
                              void* d_out, int out_size, void* d_ws, size_t ws_size,
                              hipStream_t stream) {
    const float* feat = (const float*)d_in[0];
    float* out = (float*)d_out;
    float* ws = (float*)d_ws;

    // workspace layout (floats)
    float* qn = ws;                                  // 25*640*196 = 3,136,000
    float* sn = qn + (size_t)NQ * CC * HW;           // 640*980    =   627,200
    float* S  = sn + (size_t)CC * NSL;               // 25*196*980 = 4,802,000
    float* Ts = S  + (size_t)NQ * HW * NSL;          // 4,802,000
    float* Tq = Ts + (size_t)NQ * HW * NSL;          // 4,802,000  (end: ~72.7 MB)

    k_norm<<<NQ + NWAY, 256, 0, stream>>>(feat, qn, sn);
    k_gemm<<<dim3(16, 4, NQ), 256, 0, stream>>>(qn, sn, S);
    k_ts<<<NQ * HW, 256, 0, stream>>>(S, Ts);
    k_tq<<<NQ, 1024, 0, stream>>>(S, Tq);
    k_solve<<<NQ, 256, 0, stream>>>(Ts, Tq, out);
}

// Round 2
// 978.767 us; speedup vs baseline: 6.8900x; 6.8900x over previous
//
#include <hip/hip_runtime.h>
#include <math.h>

// Problem constants
#define NQ     25      // number of query images (= n_support)
#define NWAY   5
#define KSHOT  5
#define CC     640     // channels
#define HW     196     // 14*14
#define NSL    980     // NWAY*HW support locations
#define GAMMA  20.0f
#define GAMMA2 10.0f
#define NITER  12      // ||0.25*M||_1 = 0.25 -> 0.25^12 ~ 6e-8, threshold 1.77e-2

// ---------------------------------------------------------------------------
// K1: prototype mean + per-spatial-location L2 normalization.
// ---------------------------------------------------------------------------
__global__ __launch_bounds__(256) void k_norm(const float* __restrict__ feat,
                                              float* __restrict__ qn,
                                              float* __restrict__ sn) {
    const int b = blockIdx.x;
    const int t = threadIdx.x;
    if (t >= HW) return;
    if (b < NQ) {
        const float* f = feat + (size_t)(NQ + b) * CC * HW;
        float ss = 0.f;
        for (int c = 0; c < CC; ++c) { float x = f[c * HW + t]; ss += x * x; }
        const float inv = 1.f / (1e-16f + sqrtf(ss));
        float* o = qn + (size_t)b * CC * HW;
        for (int c = 0; c < CC; ++c) o[c * HW + t] = f[c * HW + t] * inv;
    } else {
        const int s = b - NQ;
        const float* f = feat + (size_t)(NQ + s * KSHOT) * CC * HW;
        const size_t img = (size_t)CC * HW;
        float ss = 0.f;
        for (int c = 0; c < CC; ++c) {
            float m = 0.2f * (f[c * HW + t] + f[img + c * HW + t] + f[2 * img + c * HW + t]
                              + f[3 * img + c * HW + t] + f[4 * img + c * HW + t]);
            sn[c * NSL + s * HW + t] = m;
            ss += m * m;
        }
        const float inv = 1.f / (1e-16f + sqrtf(ss));
        for (int c = 0; c < CC; ++c) sn[c * NSL + s * HW + t] *= inv;
    }
}

// ---------------------------------------------------------------------------
// K2: S[q][m][j] = sum_c qn[q][c][m] * sn[c][j]   (TN GEMM, 64x64 tile, BK=16)
// ---------------------------------------------------------------------------
__global__ __launch_bounds__(256) void k_gemm(const float* __restrict__ qn,
                                              const float* __restrict__ sn,
                                              float* __restrict__ S) {
    const int q  = blockIdx.z;
    const int m0 = blockIdx.y * 64;
    const int n0 = blockIdx.x * 64;
    const float* A = qn + (size_t)q * CC * HW;
    __shared__ float As[16][64];
    __shared__ float Bs[16][64];
    const int t  = threadIdx.x;
    const int tx = t & 15, ty = t >> 4;
    float acc[4][4] = {{0.f}};
    for (int c0 = 0; c0 < CC; c0 += 16) {
#pragma unroll
        for (int p = 0; p < 4; ++p) {
            int idx = t + p * 256;
            int k = idx >> 6, i = idx & 63;
            int m = m0 + i;
            As[k][i] = (m < HW) ? A[(c0 + k) * HW + m] : 0.f;
            int j = n0 + i;
            Bs[k][i] = (j < NSL) ? sn[(c0 + k) * NSL + j] : 0.f;
        }
        __syncthreads();
#pragma unroll
        for (int k = 0; k < 16; ++k) {
            float a[4], bb[4];
#pragma unroll
            for (int i = 0; i < 4; ++i) a[i] = As[k][ty * 4 + i];
#pragma unroll
            for (int j = 0; j < 4; ++j) bb[j] = Bs[k][tx * 4 + j];
#pragma unroll
            for (int i = 0; i < 4; ++i)
#pragma unroll
                for (int j = 0; j < 4; ++j) acc[i][j] += a[i] * bb[j];
        }
        __syncthreads();
    }
    float* Sq = S + (size_t)q * HW * NSL;
#pragma unroll
    for (int i = 0; i < 4; ++i) {
        int m = m0 + ty * 4 + i;
        if (m >= HW) continue;
#pragma unroll
        for (int j = 0; j < 4; ++j) {
            int n = n0 + tx * 4 + j;
            if (n < NSL) Sq[m * NSL + n] = acc[i][j];
        }
    }
}

// ---------------------------------------------------------------------------
// K3a: Ts[qm][j] = softmax_j(GAMMA * S[qm][:])   one block per (q,m) row
// ---------------------------------------------------------------------------
__global__ __launch_bounds__(256) void k_ts(const float* __restrict__ S,
                                            float* __restrict__ Ts) {
    const size_t qm = blockIdx.x;
    const float* row = S + qm * NSL;
    float* orow = Ts + qm * NSL;
    const int t = threadIdx.x, lane = t & 63, wv = t >> 6;
    __shared__ float redm[4], reds[4];
    float x[4];
    float mx = -1e30f;
#pragma unroll
    for (int p = 0; p < 4; ++p) {
        int j = t + p * 256;
        x[p] = (j < NSL) ? row[j] : -1e30f;
        mx = fmaxf(mx, x[p]);
    }
    for (int d = 32; d; d >>= 1) mx = fmaxf(mx, __shfl_xor(mx, d));
    if (lane == 0) redm[wv] = mx;
    __syncthreads();
    mx = fmaxf(fmaxf(redm[0], redm[1]), fmaxf(redm[2], redm[3]));
    float e[4], sum = 0.f;
#pragma unroll
    for (int p = 0; p < 4; ++p) {
        e[p] = expf(GAMMA * (x[p] - mx));
        sum += e[p];
    }
    for (int d = 32; d; d >>= 1) sum += __shfl_xor(sum, d);
    if (lane == 0) reds[wv] = sum;
    __syncthreads();
    const float inv = 1.f / (reds[0] + reds[1] + reds[2] + reds[3]);
#pragma unroll
    for (int p = 0; p < 4; ++p) {
        int j = t + p * 256;
        if (j < NSL) orow[j] = e[p] * inv;
    }
}

// ---------------------------------------------------------------------------
// K3b: Tq[q][m][j] = softmax over m of (GAMMA2 * S[q][:,j]); thread per column
// ---------------------------------------------------------------------------
__global__ __launch_bounds__(1024) void k_tq(const float* __restrict__ S,
                                             float* __restrict__ Tq) {
    const int q = blockIdx.x;
    const int j = threadIdx.x;
    if (j >= NSL) return;
    const float* base = S + (size_t)q * HW * NSL;
    float mx = -1e30f;
    for (int m = 0; m < HW; ++m) mx = fmaxf(mx, base[m * NSL + j]);
    float sum = 0.f;
    for (int m = 0; m < HW; ++m) sum += expf(GAMMA2 * (base[m * NSL + j] - mx));
    const float inv = 1.f / sum;
    float* o = Tq + (size_t)q * HW * NSL;
    for (int m = 0; m < HW; ++m) o[m * NSL + j] = expf(GAMMA2 * (base[m * NSL + j] - mx)) * inv;
}

// ---------------------------------------------------------------------------
// K4: M[q] = 0.25 * Tq[q] (196x980) * Ts[q]^T (980x196)   (NT GEMM, K=980)
// 64x64 tile, BK=16, 256 threads, 4x4 per thread.
// ---------------------------------------------------------------------------
__global__ __launch_bounds__(256) void k_mgemm(const float* __restrict__ Tq,
                                               const float* __restrict__ Ts,
                                               float* __restrict__ M) {
    const int q  = blockIdx.z;
    const int i0 = blockIdx.y * 64;
    const int j0 = blockIdx.x * 64;
    const float* A = Tq + (size_t)q * HW * NSL;
    const float* B = Ts + (size_t)q * HW * NSL;
    __shared__ float As[16][68];
    __shared__ float Bs[16][68];
    const int t  = threadIdx.x;
    const int tx = t & 15, ty = t >> 4;
    float acc[4][4] = {{0.f}};
    for (int c0 = 0; c0 < NSL; c0 += 16) {
#pragma unroll
        for (int p = 0; p < 4; ++p) {
            int idx = p * 256 + t;
            int k = idx & 15, r = idx >> 4;
            int kk = c0 + k;
            int ia = i0 + r;
            As[k][r] = (ia < HW && kk < NSL) ? A[ia * NSL + kk] : 0.f;
            int jb = j0 + r;
            Bs[k][r] = (jb < HW && kk < NSL) ? B[jb * NSL + kk] : 0.f;
        }
        __syncthreads();
#pragma unroll
        for (int k = 0; k < 16; ++k) {
            float a[4], bb[4];
#pragma unroll
            for (int i = 0; i < 4; ++i) a[i] = As[k][ty * 4 + i];
#pragma unroll
            for (int j = 0; j < 4; ++j) bb[j] = Bs[k][tx * 4 + j];
#pragma unroll
            for (int i = 0; i < 4; ++i)
#pragma unroll
                for (int j = 0; j < 4; ++j) acc[i][j] += a[i] * bb[j];
        }
        __syncthreads();
    }
    float* Mq = M + (size_t)q * HW * HW;
#pragma unroll
    for (int i = 0; i < 4; ++i) {
        int ii = i0 + ty * 4 + i;
        if (ii >= HW) continue;
#pragma unroll
        for (int j = 0; j < 4; ++j) {
            int jj = j0 + tx * 4 + j;
            if (jj < HW) Mq[ii * HW + jj] = 0.25f * acc[i][j];
        }
    }
}

// ---------------------------------------------------------------------------
// K5: rhs[q][m] = 1 + 0.5 * rowsum(Tq[q][m][:])
//     R[q][s][m] = sum_n Ts[q][m][s*HW + n]   (class-partial row sums of Ts)
// ---------------------------------------------------------------------------
__global__ __launch_bounds__(256) void k_prep(const float* __restrict__ Tq,
                                              const float* __restrict__ Ts,
                                              float* __restrict__ rhs,
                                              float* __restrict__ R) {
    const int q = blockIdx.x;
    const float* tq = Tq + (size_t)q * HW * NSL;
    const float* ts = Ts + (size_t)q * HW * NSL;
    const int t = threadIdx.x, lane = t & 63, wv = t >> 6;
    for (int m = wv; m < HW; m += 4) {
        float s = 0.f;
        for (int j = lane; j < NSL; j += 64) s += tq[m * NSL + j];
        for (int d = 32; d; d >>= 1) s += __shfl_xor(s, d);
        if (lane == 0) rhs[q * HW + m] = 1.f + 0.5f * s;
    }
    for (int m = wv; m < HW; m += 4) {
        float s5[NWAY];
#pragma unroll
        for (int s = 0; s < NWAY; ++s) s5[s] = 0.f;
        for (int n = lane; n < HW; n += 64) {
#pragma unroll
            for (int s = 0; s < NWAY; ++s) s5[s] += ts[m * NSL + s * HW + n];
        }
#pragma unroll
        for (int s = 0; s < NWAY; ++s) {
            float a = s5[s];
            for (int d = 32; d; d >>= 1) a += __shfl_xor(a, d);
            if (lane == 0) R[((size_t)q * NWAY + s) * HW + m] = a;
        }
    }
}

// ---------------------------------------------------------------------------
// K6: per-query Katz solve, M in LDS.  v <- rhs + M v  (NITER times, M = 0.25*TqTs^T)
//     out[q][s] = (sum_m v[m]*R[s][m]) / total
// ---------------------------------------------------------------------------
__global__ __launch_bounds__(256) void k_solve2(const float* __restrict__ M,
                                               const float* __restrict__ rhs,
                                               const float* __restrict__ R,
                                               float* __restrict__ out) {
    const int q = blockIdx.x;
    __shared__ float Ms[HW][HW + 1];   // 196 x 197 floats, pad -> conflict-free rows
    __shared__ float va[HW], vb[HW], cls[NWAY];
    const int t = threadIdx.x;
    const float* Mq = M + (size_t)q * HW * HW;
    const float4* Mq4 = reinterpret_cast<const float4*>(Mq);
    for (int idx4 = t; idx4 < (HW * HW) / 4; idx4 += 256) {
        float4 x = Mq4[idx4];
        int base = idx4 * 4;
        int i = base / HW, j = base - i * HW;   // rows are multiples of 4 long
        Ms[i][j] = x.x; Ms[i][j + 1] = x.y; Ms[i][j + 2] = x.z; Ms[i][j + 3] = x.w;
    }
    float rr = 0.f;
    if (t < HW) { rr = rhs[q * HW + t]; va[t] = rr; }
    __syncthreads();
    for (int it = 0; it < NITER; ++it) {
        const float* src = (it & 1) ? vb : va;
        float* dst = (it & 1) ? va : vb;
        if (t < HW) {
            float a = 0.f;
#pragma unroll 4
            for (int j = 0; j < HW; ++j) a += Ms[t][j] * src[j];
            dst[t] = rr + a;
        }
        __syncthreads();
    }
    // NITER even -> result in va
    const int lane = t & 63, wv = t >> 6;
    for (int s = wv; s < NWAY; s += 4) {
        float a = 0.f;
        const float* Rs = R + ((size_t)q * NWAY + s) * HW;
        for (int m = lane; m < HW; m += 64) a += va[m] * Rs[m];
        for (int d = 32; d; d >>= 1) a += __shfl_xor(a, d);
        if (lane == 0) cls[s] = a;
    }
    __syncthreads();
    if (t == 0) {
        float tot = cls[0] + cls[1] + cls[2] + cls[3] + cls[4];
        float invt = 1.f / tot;
        for (int s = 0; s < NWAY; ++s) out[q * NWAY + s] = cls[s] * invt;
    }
}

// ---------------------------------------------------------------------------
extern "C" void kernel_launch(void* const* d_in, const int* in_sizes, int n_in,
                              void* d_out, int out_size, void* d_ws, size_t ws_size,
                              hipStream_t stream) {
    const float* feat = (const float*)d_in[0];
    float* out = (float*)d_out;
    float* ws = (float*)d_ws;

    // workspace layout (floats)
    float* qn = ws;                                  // 25*640*196 = 3,136,000
    float* sn = qn + (size_t)NQ * CC * HW;           // 640*980    =   627,200
    float* S  = sn + (size_t)CC * NSL;               // 25*196*980 = 4,802,000
    float* Ts = S  + (size_t)NQ * HW * NSL;          // 4,802,000
    float* Tq = Ts + (size_t)NQ * HW * NSL;          // 4,802,000  (end ~72.7 MB)
    // S is dead after the softmaxes -> reuse its region for M / rhs / R
    float* M   = S;                                  // 25*196*196 = 960,400
    float* rhs = M + (size_t)NQ * HW * HW;           // 25*196     = 4,900
    float* R   = rhs + (size_t)NQ * HW;              // 25*5*196   = 24,500

    k_norm <<<NQ + NWAY, 256, 0, stream>>>(feat, qn, sn);
    k_gemm <<<dim3(16, 4, NQ), 256, 0, stream>>>(qn, sn, S);
    k_ts   <<<NQ * HW, 256, 0, stream>>>(S, Ts);
    k_tq   <<<NQ, 1024, 0, stream>>>(S, Tq);
    k_mgemm<<<dim3(4, 4, NQ), 256, 0, stream>>>(Tq, Ts, M);
    k_prep <<<NQ, 256, 0, stream>>>(Tq, Ts, rhs, R);
    k_solve2<<<NQ, 256, 0, stream>>>(M, rhs, R, out);
}

// Round 3
// 452.548 us; speedup vs baseline: 14.9015x; 2.1628x over previous
//
#include <hip/hip_runtime.h>
#include <math.h>

// Problem constants
#define NQ     25      // number of query images (= n_support)
#define NWAY   5
#define KSHOT  5
#define CC     640     // channels
#define HW     196     // 14*14
#define NSL    980     // NWAY*HW support locations
#define GAMMA  20.0f
#define GAMMA2 10.0f
#define NITER  12      // ||0.25*M||_1 = 0.25 -> 0.25^12 ~ 6e-8 vs threshold 1.77e-2

// ---------------------------------------------------------------------------
// K1: prototype mean + per-location L2 normalization.
// grid (13, 30): by = image/prototype, bx = 16-location tile.
// 256 threads = 16 locations (lx) x 16 channel-groups (cg), 40 ch each.
// ---------------------------------------------------------------------------
__global__ __launch_bounds__(256) void k_norm(const float* __restrict__ feat,
                                              float* __restrict__ qn,
                                              float* __restrict__ sn) {
    const int by = blockIdx.y;
    const int lx = threadIdx.x & 15;
    const int cg = threadIdx.x >> 4;
    const int l  = blockIdx.x * 16 + lx;
    const bool act = (l < HW);
    const int c0 = cg * 40;
    __shared__ float pr[16][17];

    float xv[40];
    float ss = 0.f;
    if (by < NQ) {
        const float* f = feat + (size_t)(NQ + by) * CC * HW;
#pragma unroll
        for (int i = 0; i < 40; ++i) {
            float x = act ? f[(c0 + i) * HW + l] : 0.f;
            xv[i] = x; ss += x * x;
        }
        pr[cg][lx] = ss;
        __syncthreads();
        if (cg == 0) {
            float a = 0.f;
#pragma unroll
            for (int k = 0; k < 16; ++k) a += pr[k][lx];
            pr[0][lx] = 1.f / (1e-16f + sqrtf(a));
        }
        __syncthreads();
        const float inv = pr[0][lx];
        float* o = qn + (size_t)by * CC * HW;
        if (act) {
#pragma unroll
            for (int i = 0; i < 40; ++i) o[(c0 + i) * HW + l] = xv[i] * inv;
        }
    } else {
        const int s = by - NQ;
        const float* f = feat + (size_t)(NQ + s * KSHOT) * CC * HW;
        const size_t img = (size_t)CC * HW;
#pragma unroll
        for (int i = 0; i < 40; ++i) {
            float m = 0.f;
            if (act) {
                const float* p = f + (c0 + i) * HW + l;
                m = 0.2f * (p[0] + p[img] + p[2 * img] + p[3 * img] + p[4 * img]);
            }
            xv[i] = m; ss += m * m;
        }
        pr[cg][lx] = ss;
        __syncthreads();
        if (cg == 0) {
            float a = 0.f;
#pragma unroll
            for (int k = 0; k < 16; ++k) a += pr[k][lx];
            pr[0][lx] = 1.f / (1e-16f + sqrtf(a));
        }
        __syncthreads();
        const float inv = pr[0][lx];
        if (act) {
#pragma unroll
            for (int i = 0; i < 40; ++i) sn[(c0 + i) * NSL + s * HW + l] = xv[i] * inv;
        }
    }
}

// ---------------------------------------------------------------------------
// K2: S[q][m][j] = sum_c qn[q][c][m] * sn[c][j]   (TN GEMM, 64x64 tile, BK=16)
// ---------------------------------------------------------------------------
__global__ __launch_bounds__(256) void k_gemm(const float* __restrict__ qn,
                                              const float* __restrict__ sn,
                                              float* __restrict__ S) {
    const int q  = blockIdx.z;
    const int m0 = blockIdx.y * 64;
    const int n0 = blockIdx.x * 64;
    const float* A = qn + (size_t)q * CC * HW;
    __shared__ float As[16][64];
    __shared__ float Bs[16][64];
    const int t  = threadIdx.x;
    const int tx = t & 15, ty = t >> 4;
    float acc[4][4] = {{0.f}};
    for (int c0 = 0; c0 < CC; c0 += 16) {
#pragma unroll
        for (int p = 0; p < 4; ++p) {
            int idx = t + p * 256;
            int k = idx >> 6, i = idx & 63;
            int m = m0 + i;
            As[k][i] = (m < HW) ? A[(c0 + k) * HW + m] : 0.f;
            int j = n0 + i;
            Bs[k][i] = (j < NSL) ? sn[(c0 + k) * NSL + j] : 0.f;
        }
        __syncthreads();
#pragma unroll
        for (int k = 0; k < 16; ++k) {
            float a[4], bb[4];
#pragma unroll
            for (int i = 0; i < 4; ++i) a[i] = As[k][ty * 4 + i];
#pragma unroll
            for (int j = 0; j < 4; ++j) bb[j] = Bs[k][tx * 4 + j];
#pragma unroll
            for (int i = 0; i < 4; ++i)
#pragma unroll
                for (int j = 0; j < 4; ++j) acc[i][j] += a[i] * bb[j];
        }
        __syncthreads();
    }
    float* Sq = S + (size_t)q * HW * NSL;
#pragma unroll
    for (int i = 0; i < 4; ++i) {
        int m = m0 + ty * 4 + i;
        if (m >= HW) continue;
#pragma unroll
        for (int j = 0; j < 4; ++j) {
            int n = n0 + tx * 4 + j;
            if (n < NSL) Sq[m * NSL + n] = acc[i][j];
        }
    }
}

// ---------------------------------------------------------------------------
// K3a: Ts[qm][j] = softmax_j(GAMMA * S[qm][:]) + fused class row-sums
//      R[q][s][m] = sum_n Ts[qm][s*HW+n].   One block per (q,m) row.
// ---------------------------------------------------------------------------
__global__ __launch_bounds__(256) void k_ts(const float* __restrict__ S,
                                            float* __restrict__ Ts,
                                            float* __restrict__ R) {
    const int qm = blockIdx.x;
    const int q = qm / HW, m = qm - q * HW;
    const float* row = S + (size_t)qm * NSL;
    float* orow = Ts + (size_t)qm * NSL;
    const int t = threadIdx.x, lane = t & 63, wv = t >> 6;
    __shared__ float redm[4], reds[4], rred[NWAY][4];
    float x[4];
    float mx = -1e30f;
#pragma unroll
    for (int p = 0; p < 4; ++p) {
        int j = t + p * 256;
        x[p] = (j < NSL) ? row[j] : -1e30f;
        mx = fmaxf(mx, x[p]);
    }
    for (int d = 32; d; d >>= 1) mx = fmaxf(mx, __shfl_xor(mx, d));
    if (lane == 0) redm[wv] = mx;
    __syncthreads();
    mx = fmaxf(fmaxf(redm[0], redm[1]), fmaxf(redm[2], redm[3]));
    float e[4], sum = 0.f;
#pragma unroll
    for (int p = 0; p < 4; ++p) {
        e[p] = expf(GAMMA * (x[p] - mx));
        sum += e[p];
    }
    for (int d = 32; d; d >>= 1) sum += __shfl_xor(sum, d);
    if (lane == 0) reds[wv] = sum;
    __syncthreads();
    const float inv = 1.f / (reds[0] + reds[1] + reds[2] + reds[3]);
    float racc[NWAY];
#pragma unroll
    for (int s = 0; s < NWAY; ++s) racc[s] = 0.f;
#pragma unroll
    for (int p = 0; p < 4; ++p) {
        int j = t + p * 256;
        if (j < NSL) {
            float val = e[p] * inv;
            orow[j] = val;
            int cls = j / HW;
#pragma unroll
            for (int s = 0; s < NWAY; ++s) racc[s] += (cls == s) ? val : 0.f;
        }
    }
#pragma unroll
    for (int s = 0; s < NWAY; ++s) {
        float a = racc[s];
        for (int d = 32; d; d >>= 1) a += __shfl_xor(a, d);
        if (lane == 0) rred[s][wv] = a;
    }
    __syncthreads();
    if (t < NWAY)
        R[((size_t)q * NWAY + t) * HW + m] =
            rred[t][0] + rred[t][1] + rred[t][2] + rred[t][3];
}

// ---------------------------------------------------------------------------
// K3b: Tq[q][m][j] = softmax over m of (GAMMA2 * S[q][:,j])
// grid (16, 25): 64 columns per block, 4 m-groups of 49; exp cached in regs.
// ---------------------------------------------------------------------------
__global__ __launch_bounds__(256) void k_tq(const float* __restrict__ S,
                                            float* __restrict__ Tq) {
    const int q  = blockIdx.y;
    const int tx = threadIdx.x & 63;
    const int tg = threadIdx.x >> 6;           // m-group 0..3
    const int j  = blockIdx.x * 64 + tx;
    const int m0 = tg * 49;
    const float* base = S + (size_t)q * HW * NSL;
    __shared__ float rmax[4][64], rsum[4][64];
    float xv[49];
    float mx = -1e30f;
    if (j < NSL) {
#pragma unroll
        for (int i = 0; i < 49; ++i) {
            xv[i] = base[(m0 + i) * NSL + j];
            mx = fmaxf(mx, xv[i]);
        }
    }
    rmax[tg][tx] = mx;
    __syncthreads();
    mx = fmaxf(fmaxf(rmax[0][tx], rmax[1][tx]), fmaxf(rmax[2][tx], rmax[3][tx]));
    float sum = 0.f;
    if (j < NSL) {
#pragma unroll
        for (int i = 0; i < 49; ++i) {
            xv[i] = expf(GAMMA2 * (xv[i] - mx));
            sum += xv[i];
        }
    }
    rsum[tg][tx] = sum;
    __syncthreads();
    const float inv = 1.f / (rsum[0][tx] + rsum[1][tx] + rsum[2][tx] + rsum[3][tx]);
    if (j < NSL) {
        float* o = Tq + (size_t)q * HW * NSL;
#pragma unroll
        for (int i = 0; i < 49; ++i) o[(m0 + i) * NSL + j] = xv[i] * inv;
    }
}

// ---------------------------------------------------------------------------
// K3c: rhs[qm] = 1 + 0.5 * rowsum(Tq[qm][:]).  One block per (q,m) row.
// ---------------------------------------------------------------------------
__global__ __launch_bounds__(256) void k_rhs(const float* __restrict__ Tq,
                                             float* __restrict__ rhs) {
    const int qm = blockIdx.x;
    const float* row = Tq + (size_t)qm * NSL;
    const int t = threadIdx.x, lane = t & 63, wv = t >> 6;
    __shared__ float red[4];
    float s = 0.f;
#pragma unroll
    for (int p = 0; p < 4; ++p) {
        int j = t + p * 256;
        if (j < NSL) s += row[j];
    }
    for (int d = 32; d; d >>= 1) s += __shfl_xor(s, d);
    if (lane == 0) red[wv] = s;
    __syncthreads();
    if (t == 0) rhs[qm] = 1.f + 0.5f * (red[0] + red[1] + red[2] + red[3]);
}

// ---------------------------------------------------------------------------
// K4: M[q] = 0.25 * Tq[q] (196x980) * Ts[q]^T (980x196)   (NT GEMM, K=980)
// ---------------------------------------------------------------------------
__global__ __launch_bounds__(256) void k_mgemm(const float* __restrict__ Tq,
                                               const float* __restrict__ Ts,
                                               float* __restrict__ M) {
    const int q  = blockIdx.z;
    const int i0 = blockIdx.y * 64;
    const int j0 = blockIdx.x * 64;
    const float* A = Tq + (size_t)q * HW * NSL;
    const float* B = Ts + (size_t)q * HW * NSL;
    __shared__ float As[16][68];
    __shared__ float Bs[16][68];
    const int t  = threadIdx.x;
    const int tx = t & 15, ty = t >> 4;
    float acc[4][4] = {{0.f}};
    for (int c0 = 0; c0 < NSL; c0 += 16) {
#pragma unroll
        for (int p = 0; p < 4; ++p) {
            int idx = p * 256 + t;
            int k = idx & 15, r = idx >> 4;
            int kk = c0 + k;
            int ia = i0 + r;
            As[k][r] = (ia < HW && kk < NSL) ? A[ia * NSL + kk] : 0.f;
            int jb = j0 + r;
            Bs[k][r] = (jb < HW && kk < NSL) ? B[jb * NSL + kk] : 0.f;
        }
        __syncthreads();
#pragma unroll
        for (int k = 0; k < 16; ++k) {
            float a[4], bb[4];
#pragma unroll
            for (int i = 0; i < 4; ++i) a[i] = As[k][ty * 4 + i];
#pragma unroll
            for (int j = 0; j < 4; ++j) bb[j] = Bs[k][tx * 4 + j];
#pragma unroll
            for (int i = 0; i < 4; ++i)
#pragma unroll
                for (int j = 0; j < 4; ++j) acc[i][j] += a[i] * bb[j];
        }
        __syncthreads();
    }
    float* Mq = M + (size_t)q * HW * HW;
#pragma unroll
    for (int i = 0; i < 4; ++i) {
        int ii = i0 + ty * 4 + i;
        if (ii >= HW) continue;
#pragma unroll
        for (int j = 0; j < 4; ++j) {
            int jj = j0 + tx * 4 + j;
            if (jj < HW) Mq[ii * HW + jj] = 0.25f * acc[i][j];
        }
    }
}

// ---------------------------------------------------------------------------
// K6: per-query Katz solve, M in LDS.  v <- rhs + M v  (NITER times)
//     out[q][s] = (sum_m v[m]*R[s][m]) / total
// ---------------------------------------------------------------------------
__global__ __launch_bounds__(256) void k_solve2(const float* __restrict__ M,
                                               const float* __restrict__ rhs,
                                               const float* __restrict__ R,
                                               float* __restrict__ out) {
    const int q = blockIdx.x;
    __shared__ float Ms[HW][HW + 1];
    __shared__ float va[HW], vb[HW], cls[NWAY];
    const int t = threadIdx.x;
    const float* Mq = M + (size_t)q * HW * HW;
    const float4* Mq4 = reinterpret_cast<const float4*>(Mq);
    for (int idx4 = t; idx4 < (HW * HW) / 4; idx4 += 256) {
        float4 x = Mq4[idx4];
        int base = idx4 * 4;
        int i = base / HW, j = base - i * HW;
        Ms[i][j] = x.x; Ms[i][j + 1] = x.y; Ms[i][j + 2] = x.z; Ms[i][j + 3] = x.w;
    }
    float rr = 0.f;
    if (t < HW) { rr = rhs[q * HW + t]; va[t] = rr; }
    __syncthreads();
    for (int it = 0; it < NITER; ++it) {
        const float* src = (it & 1) ? vb : va;
        float* dst = (it & 1) ? va : vb;
        if (t < HW) {
            float a = 0.f;
#pragma unroll 4
            for (int j = 0; j < HW; ++j) a += Ms[t][j] * src[j];
            dst[t] = rr + a;
        }
        __syncthreads();
    }
    const int lane = t & 63, wv = t >> 6;
    for (int s = wv; s < NWAY; s += 4) {
        float a = 0.f;
        const float* Rs = R + ((size_t)q * NWAY + s) * HW;
        for (int m = lane; m < HW; m += 64) a += va[m] * Rs[m];
        for (int d = 32; d; d >>= 1) a += __shfl_xor(a, d);
        if (lane == 0) cls[s] = a;
    }
    __syncthreads();
    if (t == 0) {
        float tot = cls[0] + cls[1] + cls[2] + cls[3] + cls[4];
        float invt = 1.f / tot;
        for (int s = 0; s < NWAY; ++s) out[q * NWAY + s] = cls[s] * invt;
    }
}

// ---------------------------------------------------------------------------
extern "C" void kernel_launch(void* const* d_in, const int* in_sizes, int n_in,
                              void* d_out, int out_size, void* d_ws, size_t ws_size,
                              hipStream_t stream) {
    const float* feat = (const float*)d_in[0];
    float* out = (float*)d_out;
    float* ws = (float*)d_ws;

    // workspace layout (floats)
    float* qn = ws;                                  // 25*640*196 = 3,136,000
    float* sn = qn + (size_t)NQ * CC * HW;           // 640*980    =   627,200
    float* S  = sn + (size_t)CC * NSL;               // 25*196*980 = 4,802,000
    float* Ts = S  + (size_t)NQ * HW * NSL;          // 4,802,000
    float* Tq = Ts + (size_t)NQ * HW * NSL;          // 4,802,000  (end ~72.7 MB)
    // qn is dead after k_gemm -> rhs/R live there (do NOT alias S: k_ts reads S)
    float* rhs = qn;                                 // 25*196 = 4,900
    float* R   = rhs + (size_t)NQ * HW;              // 25*5*196 = 24,500
    // S is dead after both softmaxes -> M lives there
    float* M   = S;                                  // 25*196*196 = 960,400

    k_norm <<<dim3(13, NQ + NWAY), 256, 0, stream>>>(feat, qn, sn);
    k_gemm <<<dim3(16, 4, NQ), 256, 0, stream>>>(qn, sn, S);
    k_ts   <<<NQ * HW, 256, 0, stream>>>(S, Ts, R);
    k_tq   <<<dim3(16, NQ), 256, 0, stream>>>(S, Tq);
    k_rhs  <<<NQ * HW, 256, 0, stream>>>(Tq, rhs);
    k_mgemm<<<dim3(4, 4, NQ), 256, 0, stream>>>(Tq, Ts, M);
    k_solve2<<<NQ, 256, 0, stream>>>(M, rhs, R, out);
}

// Round 4
// 223.404 us; speedup vs baseline: 30.1860x; 2.0257x over previous
//
#include <hip/hip_runtime.h>
#include <math.h>

// Problem constants
#define NQ     25      // number of query images (= n_support)
#define NWAY   5
#define KSHOT  5
#define CC     640     // channels (k-dim of S gemm; 640 = 20*32)
#define HW     196     // 14*14
#define NSL    980     // NWAY*HW support locations
#define NSLP   992     // padded K for M-gemm (31*32)
#define RPQ    208     // padded row count per query (13*16)
#define GAMMA  20.0f
#define GAMMA2 10.0f
#define NITER  12      // ||0.25*M||_1 = 0.25 -> 0.25^12 ~ 6e-8 vs threshold 1.77e-2

typedef __bf16 bf16;
typedef __attribute__((ext_vector_type(8))) __bf16 bf16x8;
typedef __attribute__((ext_vector_type(4))) float f32x4;

// ---------------------------------------------------------------------------
// K1: prototype mean + per-location L2 normalization -> TRANSPOSED bf16.
// qnbt[q][m][c] (rows padded to RPQ, pad rows never written -> harmless),
// snbt[j][c]    (rows padded to NSLP).
// grid (13, 30): by = image/prototype, bx = 16-location tile.
// 256 threads = 16 locations (lx) x 16 channel-groups (cg), 40 ch each.
// ---------------------------------------------------------------------------
__global__ __launch_bounds__(256) void k_norm(const float* __restrict__ feat,
                                              bf16* __restrict__ qnbt,
                                              bf16* __restrict__ snbt) {
    const int by = blockIdx.y;
    const int lx = threadIdx.x & 15;
    const int cg = threadIdx.x >> 4;
    const int l  = blockIdx.x * 16 + lx;
    const bool act = (l < HW);
    const int c0 = cg * 40;
    __shared__ float pr[16][17];

    float xv[40];
    float ss = 0.f;
    if (by < NQ) {
        const float* f = feat + (size_t)(NQ + by) * CC * HW;
#pragma unroll
        for (int i = 0; i < 40; ++i) {
            float x = act ? f[(c0 + i) * HW + l] : 0.f;
            xv[i] = x; ss += x * x;
        }
    } else {
        const int s = by - NQ;
        const float* f = feat + (size_t)(NQ + s * KSHOT) * CC * HW;
        const size_t img = (size_t)CC * HW;
#pragma unroll
        for (int i = 0; i < 40; ++i) {
            float m = 0.f;
            if (act) {
                const float* p = f + (c0 + i) * HW + l;
                m = 0.2f * (p[0] + p[img] + p[2 * img] + p[3 * img] + p[4 * img]);
            }
            xv[i] = m; ss += m * m;
        }
    }
    pr[cg][lx] = ss;
    __syncthreads();
    if (cg == 0) {
        float a = 0.f;
#pragma unroll
        for (int k = 0; k < 16; ++k) a += pr[k][lx];
        pr[0][lx] = 1.f / (1e-16f + sqrtf(a));
    }
    __syncthreads();
    const float inv = pr[0][lx];
    if (act) {
        bf16* o = (by < NQ) ? (qnbt + ((size_t)by * RPQ + l) * CC)
                            : (snbt + ((size_t)(by - NQ) * HW + l) * CC);
#pragma unroll
        for (int i = 0; i < 40; ++i) o[c0 + i] = (bf16)(xv[i] * inv);
    }
}

// ---------------------------------------------------------------------------
// K2: S[q][m][j] = sum_c qnbt[q][m][c] * snbt[j][c]   via 16x16x32 bf16 MFMA.
// One wave per 16x16 output tile; fragment layouts (m89-verified D mapping):
//   A: row = lane&15, k = (lane>>4)*8 + b (contiguous bf16x8)
//   B: col = lane&15, k = (lane>>4)*8 + b
//   D: col = lane&15, row = (lane>>4)*4 + reg
// grid (62 n-tiles, 13 m-tiles, 25 q), 64 threads.
// ---------------------------------------------------------------------------
__global__ __launch_bounds__(64) void k_sgemm(const bf16* __restrict__ qnbt,
                                              const bf16* __restrict__ snbt,
                                              float* __restrict__ S) {
    const int q  = blockIdx.z;
    const int mt = blockIdx.y;
    const int nt = blockIdx.x;
    const int l  = threadIdx.x;
    const int lo = l & 15, hi = l >> 4;
    const bf16* A = qnbt + ((size_t)q * RPQ + mt * 16 + lo) * CC + hi * 8;
    const bf16* B = snbt + ((size_t)(nt * 16 + lo)) * CC + hi * 8;
    f32x4 acc = {0.f, 0.f, 0.f, 0.f};
#pragma unroll 4
    for (int k0 = 0; k0 < CC; k0 += 32) {
        bf16x8 a = *reinterpret_cast<const bf16x8*>(A + k0);
        bf16x8 b = *reinterpret_cast<const bf16x8*>(B + k0);
        acc = __builtin_amdgcn_mfma_f32_16x16x32_bf16(a, b, acc, 0, 0, 0);
    }
    const int j = nt * 16 + lo;
    if (j >= NSL) return;
    float* Sq = S + (size_t)q * HW * NSL;
#pragma unroll
    for (int r = 0; r < 4; ++r) {
        int m = mt * 16 + hi * 4 + r;
        if (m < HW) Sq[(size_t)m * NSL + j] = acc[r];
    }
}

// ---------------------------------------------------------------------------
// K3a: Ts[q][m][j] = softmax_j(GAMMA * S[qm][:]) -> bf16 (stride NSLP, pads 0)
//      + fused class row-sums R[q][s][m] (fp32).  One block per (q,m) row.
// ---------------------------------------------------------------------------
__global__ __launch_bounds__(256) void k_ts(const float* __restrict__ S,
                                            bf16* __restrict__ Ts,
                                            float* __restrict__ R) {
    const int qm = blockIdx.x;
    const int q = qm / HW, m = qm - q * HW;
    const float* row = S + (size_t)qm * NSL;
    bf16* orow = Ts + ((size_t)q * RPQ + m) * NSLP;
    const int t = threadIdx.x, lane = t & 63, wv = t >> 6;
    __shared__ float redm[4], reds[4], rred[NWAY][4];
    float x[4];
    float mx = -1e30f;
#pragma unroll
    for (int p = 0; p < 4; ++p) {
        int j = t + p * 256;
        x[p] = (j < NSL) ? row[j] : -1e30f;
        mx = fmaxf(mx, x[p]);
    }
    for (int d = 32; d; d >>= 1) mx = fmaxf(mx, __shfl_xor(mx, d));
    if (lane == 0) redm[wv] = mx;
    __syncthreads();
    mx = fmaxf(fmaxf(redm[0], redm[1]), fmaxf(redm[2], redm[3]));
    float e[4], sum = 0.f;
#pragma unroll
    for (int p = 0; p < 4; ++p) {
        e[p] = expf(GAMMA * (x[p] - mx));
        sum += e[p];
    }
    for (int d = 32; d; d >>= 1) sum += __shfl_xor(sum, d);
    if (lane == 0) reds[wv] = sum;
    __syncthreads();
    const float inv = 1.f / (reds[0] + reds[1] + reds[2] + reds[3]);
    float racc[NWAY];
#pragma unroll
    for (int s = 0; s < NWAY; ++s) racc[s] = 0.f;
#pragma unroll
    for (int p = 0; p < 4; ++p) {
        int j = t + p * 256;
        if (j < NSL) {
            float val = e[p] * inv;
            orow[j] = (bf16)val;
            int cls = j / HW;
#pragma unroll
            for (int s = 0; s < NWAY; ++s) racc[s] += (cls == s) ? val : 0.f;
        } else if (j < NSLP) {
            orow[j] = (bf16)0.f;   // zero K-pad (feeds k_mgemm)
        }
    }
#pragma unroll
    for (int s = 0; s < NWAY; ++s) {
        float a = racc[s];
        for (int d = 32; d; d >>= 1) a += __shfl_xor(a, d);
        if (lane == 0) rred[s][wv] = a;
    }
    __syncthreads();
    if (t < NWAY)
        R[((size_t)q * NWAY + t) * HW + m] =
            rred[t][0] + rred[t][1] + rred[t][2] + rred[t][3];
}

// ---------------------------------------------------------------------------
// K3b: Tq[q][m][j] = softmax over m of (GAMMA2 * S[q][:,j]) -> bf16, pads 0.
// grid (16, 25): 64 columns per block, 4 m-groups of 49; exp cached in regs.
// ---------------------------------------------------------------------------
__global__ __launch_bounds__(256) void k_tq(const float* __restrict__ S,
                                            bf16* __restrict__ Tq) {
    const int q  = blockIdx.y;
    const int tx = threadIdx.x & 63;
    const int tg = threadIdx.x >> 6;           // m-group 0..3
    const int j  = blockIdx.x * 64 + tx;
    const int m0 = tg * 49;
    const float* base = S + (size_t)q * HW * NSL;
    bf16* ob = Tq + (size_t)q * RPQ * NSLP;
    __shared__ float rmax[4][64], rsum[4][64];
    float xv[49];
    float mx = -1e30f;
    if (j < NSL) {
#pragma unroll
        for (int i = 0; i < 49; ++i) {
            xv[i] = base[(m0 + i) * NSL + j];
            mx = fmaxf(mx, xv[i]);
        }
    }
    rmax[tg][tx] = mx;
    __syncthreads();
    mx = fmaxf(fmaxf(rmax[0][tx], rmax[1][tx]), fmaxf(rmax[2][tx], rmax[3][tx]));
    float sum = 0.f;
    if (j < NSL) {
#pragma unroll
        for (int i = 0; i < 49; ++i) {
            xv[i] = expf(GAMMA2 * (xv[i] - mx));
            sum += xv[i];
        }
    }
    rsum[tg][tx] = sum;
    __syncthreads();
    const float inv = 1.f / (rsum[0][tx] + rsum[1][tx] + rsum[2][tx] + rsum[3][tx]);
    if (j < NSL) {
#pragma unroll
        for (int i = 0; i < 49; ++i) ob[(size_t)(m0 + i) * NSLP + j] = (bf16)(xv[i] * inv);
    } else if (j < NSLP) {
#pragma unroll
        for (int i = 0; i < 49; ++i) ob[(size_t)(m0 + i) * NSLP + j] = (bf16)0.f;
    }
}

// ---------------------------------------------------------------------------
// K3c: rhs[qm] = 1 + 0.5 * rowsum(Tq[qm][:]).  One block per (q,m) row.
// ---------------------------------------------------------------------------
__global__ __launch_bounds__(256) void k_rhs(const bf16* __restrict__ Tq,
                                             float* __restrict__ rhs) {
    const int qm = blockIdx.x;
    const int q = qm / HW, m = qm - q * HW;
    const bf16* row = Tq + ((size_t)q * RPQ + m) * NSLP;
    const int t = threadIdx.x, lane = t & 63, wv = t >> 6;
    __shared__ float red[4];
    float s = 0.f;
#pragma unroll
    for (int p = 0; p < 4; ++p) {
        int j = t + p * 256;
        if (j < NSL) s += (float)row[j];
    }
    for (int d = 32; d; d >>= 1) s += __shfl_xor(s, d);
    if (lane == 0) red[wv] = s;
    __syncthreads();
    if (t == 0) rhs[qm] = 1.f + 0.5f * (red[0] + red[1] + red[2] + red[3]);
}

// ---------------------------------------------------------------------------
// K4: M[q] = 0.25 * Tq[q] (196x992) * Ts[q]^T (992x196) via bf16 MFMA.
// K-pad columns are zeroed by k_ts/k_tq; garbage pad ROWS only reach
// discarded (guarded) outputs. grid (13 j, 13 i, 25 q), 64 threads.
// ---------------------------------------------------------------------------
__global__ __launch_bounds__(64) void k_mgemm(const bf16* __restrict__ Tq,
                                              const bf16* __restrict__ Ts,
                                              float* __restrict__ M) {
    const int q  = blockIdx.z;
    const int it = blockIdx.y;
    const int jt = blockIdx.x;
    const int l  = threadIdx.x;
    const int lo = l & 15, hi = l >> 4;
    const bf16* A = Tq + ((size_t)q * RPQ + it * 16 + lo) * NSLP + hi * 8;
    const bf16* B = Ts + ((size_t)q * RPQ + jt * 16 + lo) * NSLP + hi * 8;
    f32x4 acc = {0.f, 0.f, 0.f, 0.f};
    for (int k0 = 0; k0 < NSLP; k0 += 32) {
        bf16x8 a = *reinterpret_cast<const bf16x8*>(A + k0);
        bf16x8 b = *reinterpret_cast<const bf16x8*>(B + k0);
        acc = __builtin_amdgcn_mfma_f32_16x16x32_bf16(a, b, acc, 0, 0, 0);
    }
    const int j = jt * 16 + lo;
    if (j >= HW) return;
    float* Mq = M + (size_t)q * HW * HW;
#pragma unroll
    for (int r = 0; r < 4; ++r) {
        int i = it * 16 + hi * 4 + r;
        if (i < HW) Mq[(size_t)i * HW + j] = 0.25f * acc[r];
    }
}

// ---------------------------------------------------------------------------
// K6: per-query Katz solve, M in LDS.  v <- rhs + M v  (NITER times)
//     out[q][s] = (sum_m v[m]*R[s][m]) / total
// ---------------------------------------------------------------------------
__global__ __launch_bounds__(256) void k_solve2(const float* __restrict__ M,
                                               const float* __restrict__ rhs,
                                               const float* __restrict__ R,
                                               float* __restrict__ out) {
    const int q = blockIdx.x;
    __shared__ float Ms[HW][HW + 1];
    __shared__ float va[HW], vb[HW], cls[NWAY];
    const int t = threadIdx.x;
    const float* Mq = M + (size_t)q * HW * HW;
    const float4* Mq4 = reinterpret_cast<const float4*>(Mq);
    for (int idx4 = t; idx4 < (HW * HW) / 4; idx4 += 256) {
        float4 x = Mq4[idx4];
        int base = idx4 * 4;
        int i = base / HW, j = base - i * HW;
        Ms[i][j] = x.x; Ms[i][j + 1] = x.y; Ms[i][j + 2] = x.z; Ms[i][j + 3] = x.w;
    }
    float rr = 0.f;
    if (t < HW) { rr = rhs[q * HW + t]; va[t] = rr; }
    __syncthreads();
    for (int it = 0; it < NITER; ++it) {
        const float* src = (it & 1) ? vb : va;
        float* dst = (it & 1) ? va : vb;
        if (t < HW) {
            float a = 0.f;
#pragma unroll 4
            for (int j = 0; j < HW; ++j) a += Ms[t][j] * src[j];
            dst[t] = rr + a;
        }
        __syncthreads();
    }
    const int lane = t & 63, wv = t >> 6;
    for (int s = wv; s < NWAY; s += 4) {
        float a = 0.f;
        const float* Rs = R + ((size_t)q * NWAY + s) * HW;
        for (int m = lane; m < HW; m += 64) a += va[m] * Rs[m];
        for (int d = 32; d; d >>= 1) a += __shfl_xor(a, d);
        if (lane == 0) cls[s] = a;
    }
    __syncthreads();
    if (t == 0) {
        float tot = cls[0] + cls[1] + cls[2] + cls[3] + cls[4];
        float invt = 1.f / tot;
        for (int s = 0; s < NWAY; ++s) out[q * NWAY + s] = cls[s] * invt;
    }
}

// ---------------------------------------------------------------------------
extern "C" void kernel_launch(void* const* d_in, const int* in_sizes, int n_in,
                              void* d_out, int out_size, void* d_ws, size_t ws_size,
                              hipStream_t stream) {
    const float* feat = (const float*)d_in[0];
    float* out = (float*)d_out;
    char* w = (char*)d_ws;

    // workspace layout (all offsets 16B-aligned)
    float* S    = (float*)w;  w += sizeof(float) * (size_t)NQ * HW * NSL;   // 19.21 MB
    bf16*  Ts   = (bf16*)w;   w += sizeof(bf16)  * (size_t)NQ * RPQ * NSLP; // 10.32 MB
    bf16*  Tq   = (bf16*)w;   w += sizeof(bf16)  * (size_t)NQ * RPQ * NSLP; // 10.32 MB
    bf16*  qnbt = (bf16*)w;   w += sizeof(bf16)  * (size_t)NQ * RPQ * CC;   //  6.66 MB
    bf16*  snbt = (bf16*)w;   w += sizeof(bf16)  * (size_t)NSLP * CC;       //  1.27 MB
    float* rhs  = (float*)w;  w += sizeof(float) * (size_t)NQ * HW;
    float* R    = (float*)w;  w += sizeof(float) * (size_t)NQ * NWAY * HW;
    // S is dead after both softmaxes -> M aliases S (0.96M floats <= 4.8M)
    float* M = S;

    k_norm  <<<dim3(13, NQ + NWAY), 256, 0, stream>>>(feat, qnbt, snbt);
    k_sgemm <<<dim3(62, 13, NQ), 64, 0, stream>>>(qnbt, snbt, S);
    k_ts    <<<NQ * HW, 256, 0, stream>>>(S, Ts, R);
    k_tq    <<<dim3(16, NQ), 256, 0, stream>>>(S, Tq);
    k_rhs   <<<NQ * HW, 256, 0, stream>>>(Tq, rhs);
    k_mgemm <<<dim3(13, 13, NQ), 64, 0, stream>>>(Tq, Ts, M);
    k_solve2<<<NQ, 256, 0, stream>>>(M, rhs, R, out);
}

// Round 5
// 163.457 us; speedup vs baseline: 41.2565x; 1.3667x over previous
//
#include <hip/hip_runtime.h>
#include <math.h>

// Problem constants
#define NQ     25      // number of query images (= n_support)
#define NWAY   5
#define KSHOT  5
#define CC     640     // channels (k-dim of S gemm; 640 = 20*32)
#define HW     196     // 14*14
#define NSL    980     // NWAY*HW support locations
#define NSLP   992     // padded K for M-gemm (31*32)
#define RPQ    208     // padded row count per query (13*16)
#define GAMMA  20.0f
#define GAMMA2 10.0f
#define NITER  12      // ||0.25*M||_1 = 0.25 -> 0.25^12 ~ 6e-8 vs threshold 1.77e-2

typedef __bf16 bf16;
typedef __attribute__((ext_vector_type(8))) __bf16 bf16x8;
typedef __attribute__((ext_vector_type(4))) float f32x4;

// ---------------------------------------------------------------------------
// K1: prototype mean + per-location L2 normalization -> TRANSPOSED bf16.
// qnbt[q][m][c] (rows padded to RPQ), snbt[j][c] (rows padded to NSLP).
// ---------------------------------------------------------------------------
__global__ __launch_bounds__(256) void k_norm(const float* __restrict__ feat,
                                              bf16* __restrict__ qnbt,
                                              bf16* __restrict__ snbt) {
    const int by = blockIdx.y;
    const int lx = threadIdx.x & 15;
    const int cg = threadIdx.x >> 4;
    const int l  = blockIdx.x * 16 + lx;
    const bool act = (l < HW);
    const int c0 = cg * 40;
    __shared__ float pr[16][17];

    float xv[40];
    float ss = 0.f;
    if (by < NQ) {
        const float* f = feat + (size_t)(NQ + by) * CC * HW;
#pragma unroll
        for (int i = 0; i < 40; ++i) {
            float x = act ? f[(c0 + i) * HW + l] : 0.f;
            xv[i] = x; ss += x * x;
        }
    } else {
        const int s = by - NQ;
        const float* f = feat + (size_t)(NQ + s * KSHOT) * CC * HW;
        const size_t img = (size_t)CC * HW;
#pragma unroll
        for (int i = 0; i < 40; ++i) {
            float m = 0.f;
            if (act) {
                const float* p = f + (c0 + i) * HW + l;
                m = 0.2f * (p[0] + p[img] + p[2 * img] + p[3 * img] + p[4 * img]);
            }
            xv[i] = m; ss += m * m;
        }
    }
    pr[cg][lx] = ss;
    __syncthreads();
    if (cg == 0) {
        float a = 0.f;
#pragma unroll
        for (int k = 0; k < 16; ++k) a += pr[k][lx];
        pr[0][lx] = 1.f / (1e-16f + sqrtf(a));
    }
    __syncthreads();
    const float inv = pr[0][lx];
    if (act) {
        bf16* o = (by < NQ) ? (qnbt + ((size_t)by * RPQ + l) * CC)
                            : (snbt + ((size_t)(by - NQ) * HW + l) * CC);
#pragma unroll
        for (int i = 0; i < 40; ++i) o[c0 + i] = (bf16)(xv[i] * inv);
    }
}

// ---------------------------------------------------------------------------
// K2: S[q][m][j] = sum_c qnbt[q][m][c] * snbt[j][c]   via 16x16x32 bf16 MFMA.
// One wave per 64x64 output tile (4x4 sub-tiles of 16x16) -> 32 FLOP/B.
// Fragment layouts (m89-verified):
//   A: row = lane&15, k = (lane>>4)*8+b;  B: col = lane&15, same k
//   D: col = lane&15, row = (lane>>4)*4 + reg
// grid (16 n-tiles, 4 m-tiles, 25 q), 64 threads.
// Pad-row garbage only reaches guarded outputs (row/col independence of MFMA).
// ---------------------------------------------------------------------------
__global__ __launch_bounds__(64) void k_sgemm(const bf16* __restrict__ qnbt,
                                              const bf16* __restrict__ snbt,
                                              float* __restrict__ S) {
    const int q  = blockIdx.z;
    const int mt = blockIdx.y;
    const int nt = blockIdx.x;
    const int l  = threadIdx.x;
    const int lo = l & 15, hi = l >> 4;
    const bf16* Ap[4];
    const bf16* Bp[4];
#pragma unroll
    for (int mi = 0; mi < 4; ++mi)
        Ap[mi] = qnbt + ((size_t)q * RPQ + mt * 64 + mi * 16 + lo) * CC + hi * 8;
#pragma unroll
    for (int ni = 0; ni < 4; ++ni)
        Bp[ni] = snbt + ((size_t)(nt * 64 + ni * 16 + lo)) * CC + hi * 8;

    f32x4 acc[4][4] = {};
#pragma unroll 2
    for (int k0 = 0; k0 < CC; k0 += 32) {
        bf16x8 a[4], b[4];
#pragma unroll
        for (int mi = 0; mi < 4; ++mi) a[mi] = *reinterpret_cast<const bf16x8*>(Ap[mi] + k0);
#pragma unroll
        for (int ni = 0; ni < 4; ++ni) b[ni] = *reinterpret_cast<const bf16x8*>(Bp[ni] + k0);
#pragma unroll
        for (int mi = 0; mi < 4; ++mi)
#pragma unroll
            for (int ni = 0; ni < 4; ++ni)
                acc[mi][ni] = __builtin_amdgcn_mfma_f32_16x16x32_bf16(a[mi], b[ni], acc[mi][ni], 0, 0, 0);
    }

    float* Sq = S + (size_t)q * HW * NSL;
#pragma unroll
    for (int mi = 0; mi < 4; ++mi) {
#pragma unroll
        for (int ni = 0; ni < 4; ++ni) {
            const int j = nt * 64 + ni * 16 + lo;
            if (j >= NSL) continue;
#pragma unroll
            for (int r = 0; r < 4; ++r) {
                int m = mt * 64 + mi * 16 + hi * 4 + r;
                if (m < HW) Sq[(size_t)m * NSL + j] = acc[mi][ni][r];
            }
        }
    }
}

// ---------------------------------------------------------------------------
// K3a: Ts[q][m][j] = softmax_j(GAMMA * S[qm][:]) -> bf16 (stride NSLP, pads 0)
//      + fused class row-sums R[q][s][m] (fp32).  One block per (q,m) row.
// ---------------------------------------------------------------------------
__global__ __launch_bounds__(256) void k_ts(const float* __restrict__ S,
                                            bf16* __restrict__ Ts,
                                            float* __restrict__ R) {
    const int qm = blockIdx.x;
    const int q = qm / HW, m = qm - q * HW;
    const float* row = S + (size_t)qm * NSL;
    bf16* orow = Ts + ((size_t)q * RPQ + m) * NSLP;
    const int t = threadIdx.x, lane = t & 63, wv = t >> 6;
    __shared__ float redm[4], reds[4], rred[NWAY][4];
    float x[4];
    float mx = -1e30f;
#pragma unroll
    for (int p = 0; p < 4; ++p) {
        int j = t + p * 256;
        x[p] = (j < NSL) ? row[j] : -1e30f;
        mx = fmaxf(mx, x[p]);
    }
    for (int d = 32; d; d >>= 1) mx = fmaxf(mx, __shfl_xor(mx, d));
    if (lane == 0) redm[wv] = mx;
    __syncthreads();
    mx = fmaxf(fmaxf(redm[0], redm[1]), fmaxf(redm[2], redm[3]));
    float e[4], sum = 0.f;
#pragma unroll
    for (int p = 0; p < 4; ++p) {
        e[p] = expf(GAMMA * (x[p] - mx));
        sum += e[p];
    }
    for (int d = 32; d; d >>= 1) sum += __shfl_xor(sum, d);
    if (lane == 0) reds[wv] = sum;
    __syncthreads();
    const float inv = 1.f / (reds[0] + reds[1] + reds[2] + reds[3]);
    float racc[NWAY];
#pragma unroll
    for (int s = 0; s < NWAY; ++s) racc[s] = 0.f;
#pragma unroll
    for (int p = 0; p < 4; ++p) {
        int j = t + p * 256;
        if (j < NSL) {
            float val = e[p] * inv;
            orow[j] = (bf16)val;
            int cls = j / HW;
#pragma unroll
            for (int s = 0; s < NWAY; ++s) racc[s] += (cls == s) ? val : 0.f;
        } else if (j < NSLP) {
            orow[j] = (bf16)0.f;   // zero K-pad (feeds k_mgemm)
        }
    }
#pragma unroll
    for (int s = 0; s < NWAY; ++s) {
        float a = racc[s];
        for (int d = 32; d; d >>= 1) a += __shfl_xor(a, d);
        if (lane == 0) rred[s][wv] = a;
    }
    __syncthreads();
    if (t < NWAY)
        R[((size_t)q * NWAY + t) * HW + m] =
            rred[t][0] + rred[t][1] + rred[t][2] + rred[t][3];
}

// ---------------------------------------------------------------------------
// K3b: Tq[q][m][j] = softmax over m of (GAMMA2 * S[q][:,j]) -> bf16, pads 0.
// grid (16, 25): 64 columns per block, 4 m-groups of 49; exp cached in regs.
// ---------------------------------------------------------------------------
__global__ __launch_bounds__(256) void k_tq(const float* __restrict__ S,
                                            bf16* __restrict__ Tq) {
    const int q  = blockIdx.y;
    const int tx = threadIdx.x & 63;
    const int tg = threadIdx.x >> 6;           // m-group 0..3
    const int j  = blockIdx.x * 64 + tx;
    const int m0 = tg * 49;
    const float* base = S + (size_t)q * HW * NSL;
    bf16* ob = Tq + (size_t)q * RPQ * NSLP;
    __shared__ float rmax[4][64], rsum[4][64];
    float xv[49];
    float mx = -1e30f;
    if (j < NSL) {
#pragma unroll
        for (int i = 0; i < 49; ++i) {
            xv[i] = base[(m0 + i) * NSL + j];
            mx = fmaxf(mx, xv[i]);
        }
    }
    rmax[tg][tx] = mx;
    __syncthreads();
    mx = fmaxf(fmaxf(rmax[0][tx], rmax[1][tx]), fmaxf(rmax[2][tx], rmax[3][tx]));
    float sum = 0.f;
    if (j < NSL) {
#pragma unroll
        for (int i = 0; i < 49; ++i) {
            xv[i] = expf(GAMMA2 * (xv[i] - mx));
            sum += xv[i];
        }
    }
    rsum[tg][tx] = sum;
    __syncthreads();
    const float inv = 1.f / (rsum[0][tx] + rsum[1][tx] + rsum[2][tx] + rsum[3][tx]);
    if (j < NSL) {
#pragma unroll
        for (int i = 0; i < 49; ++i) ob[(size_t)(m0 + i) * NSLP + j] = (bf16)(xv[i] * inv);
    } else if (j < NSLP) {
#pragma unroll
        for (int i = 0; i < 49; ++i) ob[(size_t)(m0 + i) * NSLP + j] = (bf16)0.f;
    }
}

// ---------------------------------------------------------------------------
// K3c: rhs[qm] = 1 + 0.5 * rowsum(Tq[qm][:]).  One block per (q,m) row.
// ---------------------------------------------------------------------------
__global__ __launch_bounds__(256) void k_rhs(const bf16* __restrict__ Tq,
                                             float* __restrict__ rhs) {
    const int qm = blockIdx.x;
    const int q = qm / HW, m = qm - q * HW;
    const bf16* row = Tq + ((size_t)q * RPQ + m) * NSLP;
    const int t = threadIdx.x, lane = t & 63, wv = t >> 6;
    __shared__ float red[4];
    float s = 0.f;
#pragma unroll
    for (int p = 0; p < 4; ++p) {
        int j = t + p * 256;
        if (j < NSL) s += (float)row[j];
    }
    for (int d = 32; d; d >>= 1) s += __shfl_xor(s, d);
    if (lane == 0) red[wv] = s;
    __syncthreads();
    if (t == 0) rhs[qm] = 1.f + 0.5f * (red[0] + red[1] + red[2] + red[3]);
}

// ---------------------------------------------------------------------------
// K4: M[q] = 0.25 * Tq[q] (196x992) * Ts[q]^T (992x196) via bf16 MFMA.
// One wave per 64x64 tile (4x4 of 16x16).  K-pad cols zeroed for valid rows;
// garbage rows reach only guarded outputs. grid (4 j, 4 i, 25 q), 64 threads.
// ---------------------------------------------------------------------------
__global__ __launch_bounds__(64) void k_mgemm(const bf16* __restrict__ Tq,
                                              const bf16* __restrict__ Ts,
                                              float* __restrict__ M) {
    const int q  = blockIdx.z;
    const int it = blockIdx.y;
    const int jt = blockIdx.x;
    const int l  = threadIdx.x;
    const int lo = l & 15, hi = l >> 4;
    const bf16* Ap[4];
    const bf16* Bp[4];
#pragma unroll
    for (int mi = 0; mi < 4; ++mi)
        Ap[mi] = Tq + ((size_t)q * RPQ + it * 64 + mi * 16 + lo) * NSLP + hi * 8;
#pragma unroll
    for (int ni = 0; ni < 4; ++ni)
        Bp[ni] = Ts + ((size_t)q * RPQ + jt * 64 + ni * 16 + lo) * NSLP + hi * 8;

    f32x4 acc[4][4] = {};
#pragma unroll 2
    for (int k0 = 0; k0 < NSLP; k0 += 32) {
        bf16x8 a[4], b[4];
#pragma unroll
        for (int mi = 0; mi < 4; ++mi) a[mi] = *reinterpret_cast<const bf16x8*>(Ap[mi] + k0);
#pragma unroll
        for (int ni = 0; ni < 4; ++ni) b[ni] = *reinterpret_cast<const bf16x8*>(Bp[ni] + k0);
#pragma unroll
        for (int mi = 0; mi < 4; ++mi)
#pragma unroll
            for (int ni = 0; ni < 4; ++ni)
                acc[mi][ni] = __builtin_amdgcn_mfma_f32_16x16x32_bf16(a[mi], b[ni], acc[mi][ni], 0, 0, 0);
    }

    float* Mq = M + (size_t)q * HW * HW;
#pragma unroll
    for (int mi = 0; mi < 4; ++mi) {
#pragma unroll
        for (int ni = 0; ni < 4; ++ni) {
            const int j = jt * 64 + ni * 16 + lo;
            if (j >= HW) continue;
#pragma unroll
            for (int r = 0; r < 4; ++r) {
                int i = it * 64 + mi * 16 + hi * 4 + r;
                if (i < HW) Mq[(size_t)i * HW + j] = 0.25f * acc[mi][ni][r];
            }
        }
    }
}

// ---------------------------------------------------------------------------
// K6: per-query Katz solve, M in LDS.  v <- rhs + M v  (NITER times)
//     out[q][s] = (sum_m v[m]*R[s][m]) / total
// ---------------------------------------------------------------------------
__global__ __launch_bounds__(256) void k_solve2(const float* __restrict__ M,
                                               const float* __restrict__ rhs,
                                               const float* __restrict__ R,
                                               float* __restrict__ out) {
    const int q = blockIdx.x;
    __shared__ float Ms[HW][HW + 1];
    __shared__ float va[HW], vb[HW], cls[NWAY];
    const int t = threadIdx.x;
    const float* Mq = M + (size_t)q * HW * HW;
    const float4* Mq4 = reinterpret_cast<const float4*>(Mq);
    for (int idx4 = t; idx4 < (HW * HW) / 4; idx4 += 256) {
        float4 x = Mq4[idx4];
        int base = idx4 * 4;
        int i = base / HW, j = base - i * HW;
        Ms[i][j] = x.x; Ms[i][j + 1] = x.y; Ms[i][j + 2] = x.z; Ms[i][j + 3] = x.w;
    }
    float rr = 0.f;
    if (t < HW) { rr = rhs[q * HW + t]; va[t] = rr; }
    __syncthreads();
    for (int it = 0; it < NITER; ++it) {
        const float* src = (it & 1) ? vb : va;
        float* dst = (it & 1) ? va : vb;
        if (t < HW) {
            float a = 0.f;
#pragma unroll 4
            for (int j = 0; j < HW; ++j) a += Ms[t][j] * src[j];
            dst[t] = rr + a;
        }
        __syncthreads();
    }
    const int lane = t & 63, wv = t >> 6;
    for (int s = wv; s < NWAY; s += 4) {
        float a = 0.f;
        const float* Rs = R + ((size_t)q * NWAY + s) * HW;
        for (int m = lane; m < HW; m += 64) a += va[m] * Rs[m];
        for (int d = 32; d; d >>= 1) a += __shfl_xor(a, d);
        if (lane == 0) cls[s] = a;
    }
    __syncthreads();
    if (t == 0) {
        float tot = cls[0] + cls[1] + cls[2] + cls[3] + cls[4];
        float invt = 1.f / tot;
        for (int s = 0; s < NWAY; ++s) out[q * NWAY + s] = cls[s] * invt;
    }
}

// ---------------------------------------------------------------------------
extern "C" void kernel_launch(void* const* d_in, const int* in_sizes, int n_in,
                              void* d_out, int out_size, void* d_ws, size_t ws_size,
                              hipStream_t stream) {
    const float* feat = (const float*)d_in[0];
    float* out = (float*)d_out;
    char* w = (char*)d_ws;

    // workspace layout (all offsets 16B-aligned)
    float* S    = (float*)w;  w += sizeof(float) * (size_t)NQ * HW * NSL;   // 19.21 MB
    bf16*  Ts   = (bf16*)w;   w += sizeof(bf16)  * (size_t)NQ * RPQ * NSLP; // 10.32 MB
    bf16*  Tq   = (bf16*)w;   w += sizeof(bf16)  * (size_t)NQ * RPQ * NSLP; // 10.32 MB
    bf16*  qnbt = (bf16*)w;   w += sizeof(bf16)  * (size_t)NQ * RPQ * CC;   //  6.66 MB
    bf16*  snbt = (bf16*)w;   w += sizeof(bf16)  * (size_t)NSLP * CC;       //  1.27 MB
    float* rhs  = (float*)w;  w += sizeof(float) * (size_t)NQ * HW;
    float* R    = (float*)w;  w += sizeof(float) * (size_t)NQ * NWAY * HW;
    // S is dead after both softmaxes -> M aliases S (0.96M floats <= 4.8M)
    float* M = S;

    k_norm  <<<dim3(13, NQ + NWAY), 256, 0, stream>>>(feat, qnbt, snbt);
    k_sgemm <<<dim3(16, 4, NQ), 64, 0, stream>>>(qnbt, snbt, S);
    k_ts    <<<NQ * HW, 256, 0, stream>>>(S, Ts, R);
    k_tq    <<<dim3(16, NQ), 256, 0, stream>>>(S, Tq);
    k_rhs   <<<NQ * HW, 256, 0, stream>>>(Tq, rhs);
    k_mgemm <<<dim3(4, 4, NQ), 64, 0, stream>>>(Tq, Ts, M);
    k_solve2<<<NQ, 256, 0, stream>>>(M, rhs, R, out);
}